// Round 2
// baseline (394.276 us; speedup 1.0000x reference)
//
#include <hip/hip_runtime.h>
#include <hip/hip_bf16.h>

#define DIM 512
#define DIM2 1024
#define NGRAPH 512
#define LN_EPS 1e-5f

// ---------------------------------------------------------------------------
// K1: segment mean pooling. batch_idx is sorted, so graph g's rows form a
// contiguous range found by binary search. One block per graph, 128 threads,
// float4 columns, 8-row unroll for memory-level parallelism.
// batch_idx arrives as int32 (harness converts all integer inputs to int).
// ---------------------------------------------------------------------------
__global__ __launch_bounds__(128) void segmean_kernel(const float4* __restrict__ x4,
                                                      const int* __restrict__ bi,
                                                      float4* __restrict__ hm4,
                                                      int n_nodes) {
    const int g = blockIdx.x;
    __shared__ int sb[2];
    if (threadIdx.x < 2) {
        int v = g + (int)threadIdx.x;
        int lo = 0, hi = n_nodes;
        while (lo < hi) {
            int mid = (lo + hi) >> 1;
            if (bi[mid] < v) lo = mid + 1; else hi = mid;
        }
        sb[threadIdx.x] = lo;
    }
    __syncthreads();
    const int start = sb[0], end = sb[1];
    const int t = threadIdx.x;  // column group (4 floats)

    float4 a0 = {0,0,0,0}, a1 = {0,0,0,0}, a2 = {0,0,0,0}, a3 = {0,0,0,0};
    float4 a4 = {0,0,0,0}, a5 = {0,0,0,0}, a6 = {0,0,0,0}, a7 = {0,0,0,0};

    int r = start;
    for (; r + 8 <= end; r += 8) {
        float4 v0 = x4[(size_t)(r + 0) * 128 + t];
        float4 v1 = x4[(size_t)(r + 1) * 128 + t];
        float4 v2 = x4[(size_t)(r + 2) * 128 + t];
        float4 v3 = x4[(size_t)(r + 3) * 128 + t];
        float4 v4 = x4[(size_t)(r + 4) * 128 + t];
        float4 v5 = x4[(size_t)(r + 5) * 128 + t];
        float4 v6 = x4[(size_t)(r + 6) * 128 + t];
        float4 v7 = x4[(size_t)(r + 7) * 128 + t];
        a0.x += v0.x; a0.y += v0.y; a0.z += v0.z; a0.w += v0.w;
        a1.x += v1.x; a1.y += v1.y; a1.z += v1.z; a1.w += v1.w;
        a2.x += v2.x; a2.y += v2.y; a2.z += v2.z; a2.w += v2.w;
        a3.x += v3.x; a3.y += v3.y; a3.z += v3.z; a3.w += v3.w;
        a4.x += v4.x; a4.y += v4.y; a4.z += v4.z; a4.w += v4.w;
        a5.x += v5.x; a5.y += v5.y; a5.z += v5.z; a5.w += v5.w;
        a6.x += v6.x; a6.y += v6.y; a6.z += v6.z; a6.w += v6.w;
        a7.x += v7.x; a7.y += v7.y; a7.z += v7.z; a7.w += v7.w;
    }
    for (; r < end; ++r) {
        float4 v0 = x4[(size_t)r * 128 + t];
        a0.x += v0.x; a0.y += v0.y; a0.z += v0.z; a0.w += v0.w;
    }
    a0.x += a1.x + a2.x + a3.x + a4.x + a5.x + a6.x + a7.x;
    a0.y += a1.y + a2.y + a3.y + a4.y + a5.y + a6.y + a7.y;
    a0.z += a1.z + a2.z + a3.z + a4.z + a5.z + a6.z + a7.z;
    a0.w += a1.w + a2.w + a3.w + a4.w + a5.w + a6.w + a7.w;

    int cnt = end - start;
    float inv = 1.0f / (float)(cnt > 0 ? cnt : 1);
    float4 o;
    o.x = a0.x * inv; o.y = a0.y * inv; o.z = a0.z * inv; o.w = a0.w * inv;
    hm4[g * 128 + t] = o;
}

// ---------------------------------------------------------------------------
// K2: h1 = relu(hmean @ W1 + b1).  A-row accesses are block-uniform -> scalar
// loads; W1 reads coalesced and L2-resident.
// grid = (4 col-blocks of 256, 64 row-blocks of 8), 256 threads.
// ---------------------------------------------------------------------------
__global__ __launch_bounds__(256) void gemm1_kernel(const float* __restrict__ A,
                                                    const float* __restrict__ W1,
                                                    const float* __restrict__ b1,
                                                    float* __restrict__ h1) {
    const int col = blockIdx.x * 256 + threadIdx.x;
    const int r0 = blockIdx.y * 8;
    float acc[8] = {0,0,0,0,0,0,0,0};
#pragma unroll 8
    for (int k = 0; k < DIM; ++k) {
        float w = W1[(size_t)k * DIM2 + col];
#pragma unroll
        for (int r = 0; r < 8; ++r)
            acc[r] += A[(size_t)(r0 + r) * DIM + k] * w;
    }
    float bb = b1[col];
#pragma unroll
    for (int r = 0; r < 8; ++r) {
        float v = acc[r] + bb;
        h1[(size_t)(r0 + r) * DIM2 + col] = v > 0.0f ? v : 0.0f;
    }
}

// ---------------------------------------------------------------------------
// K3: h2 = h1 @ W2 + b2.  grid = (2 col-blocks of 256, 64 row-blocks of 8).
// ---------------------------------------------------------------------------
__global__ __launch_bounds__(256) void gemm2_kernel(const float* __restrict__ A,
                                                    const float* __restrict__ W2,
                                                    const float* __restrict__ b2,
                                                    float* __restrict__ h2) {
    const int col = blockIdx.x * 256 + threadIdx.x;
    const int r0 = blockIdx.y * 8;
    float acc[8] = {0,0,0,0,0,0,0,0};
#pragma unroll 8
    for (int k = 0; k < DIM2; ++k) {
        float w = W2[(size_t)k * DIM + col];
#pragma unroll
        for (int r = 0; r < 8; ++r)
            acc[r] += A[(size_t)(r0 + r) * DIM2 + k] * w;
    }
    float bb = b2[col];
#pragma unroll
    for (int r = 0; r < 8; ++r)
        h2[(size_t)(r0 + r) * DIM + col] = acc[r] + bb;
}

// ---------------------------------------------------------------------------
// K4: LayerNorm over last dim; writes h_vn into d_out tail (output 1).
// One block (256 thr = 4 waves) per row; shuffle + LDS reduce.
// ---------------------------------------------------------------------------
__global__ __launch_bounds__(256) void ln_kernel(const float* __restrict__ h2,
                                                 const float* __restrict__ gamma,
                                                 const float* __restrict__ beta,
                                                 float* __restrict__ out) {
    const int row = blockIdx.x;
    const int t = threadIdx.x;
    const float* hr = h2 + (size_t)row * DIM;
    float v0 = hr[t], v1 = hr[t + 256];
    float s = v0 + v1;
    float ss = v0 * v0 + v1 * v1;
#pragma unroll
    for (int off = 32; off > 0; off >>= 1) {
        s  += __shfl_xor(s,  off);
        ss += __shfl_xor(ss, off);
    }
    __shared__ float sh_s[4], sh_ss[4];
    int wid = t >> 6, lane = t & 63;
    if (lane == 0) { sh_s[wid] = s; sh_ss[wid] = ss; }
    __syncthreads();
    s  = sh_s[0] + sh_s[1] + sh_s[2] + sh_s[3];
    ss = sh_ss[0] + sh_ss[1] + sh_ss[2] + sh_ss[3];
    float mu  = s * (1.0f / DIM);
    float var = ss * (1.0f / DIM) - mu * mu;
    float rs  = rsqrtf(var + LN_EPS);
    out[(size_t)row * DIM + t]       = (v0 - mu) * rs * gamma[t]       + beta[t];
    out[(size_t)row * DIM + t + 256] = (v1 - mu) * rs * gamma[t + 256] + beta[t + 256];
}

// ---------------------------------------------------------------------------
// K5: x_new = x + h_vn[batch_idx].  float4 grid-stride; h_vn (1 MB) is
// L2/L3-resident, batch_idx row value is wave-uniform in practice.
// ---------------------------------------------------------------------------
__global__ __launch_bounds__(256) void resid_kernel(const float4* __restrict__ x4,
                                                    const int* __restrict__ bi,
                                                    const float4* __restrict__ hv4,
                                                    float4* __restrict__ out4,
                                                    int n4) {
    const int stride = gridDim.x * blockDim.x;
    for (int i = blockIdx.x * 256 + threadIdx.x; i < n4; i += stride) {
        int row = i >> 7;          // 128 float4 per row
        int c   = i & 127;
        int g   = bi[row];
        float4 xv = x4[i];
        float4 hv = hv4[(g << 7) + c];
        float4 o;
        o.x = xv.x + hv.x; o.y = xv.y + hv.y;
        o.z = xv.z + hv.z; o.w = xv.w + hv.w;
        out4[i] = o;
    }
}

extern "C" void kernel_launch(void* const* d_in, const int* in_sizes, int n_in,
                              void* d_out, int out_size, void* d_ws, size_t ws_size,
                              hipStream_t stream) {
    const float* x     = (const float*)d_in[0];
    const int*   bidx  = (const int*)d_in[1];   // int32 per harness contract
    const float* W1    = (const float*)d_in[2];
    const float* b1    = (const float*)d_in[3];
    const float* W2    = (const float*)d_in[4];
    const float* b2    = (const float*)d_in[5];
    const float* gamma = (const float*)d_in[6];
    const float* beta  = (const float*)d_in[7];

    const int n_nodes = in_sizes[1];
    const size_t x_elems = (size_t)n_nodes * DIM;

    float* out     = (float*)d_out;
    float* x_new   = out;                 // output 0: [n_nodes, 512]
    float* hvn_out = out + x_elems;       // output 1: [512, 512]

    // workspace layout (4 MB total)
    float* hmean = (float*)d_ws;                     // 512*512
    float* h1    = hmean + (size_t)NGRAPH * DIM;     // 512*1024
    float* h2    = h1 + (size_t)NGRAPH * DIM2;       // 512*512

    // K1: segment mean
    segmean_kernel<<<NGRAPH, 128, 0, stream>>>((const float4*)x, bidx,
                                               (float4*)hmean, n_nodes);
    // K2: relu(hmean @ W1 + b1)
    gemm1_kernel<<<dim3(4, 64), 256, 0, stream>>>(hmean, W1, b1, h1);
    // K3: h1 @ W2 + b2
    gemm2_kernel<<<dim3(2, 64), 256, 0, stream>>>(h1, W2, b2, h2);
    // K4: LayerNorm -> output 1 (also consumed by K5)
    ln_kernel<<<NGRAPH, 256, 0, stream>>>(h2, gamma, beta, hvn_out);
    // K5: residual broadcast add -> output 0
    const int n4 = (int)(x_elems / 4);
    resid_kernel<<<4096, 256, 0, stream>>>((const float4*)x, bidx,
                                           (const float4*)hvn_out,
                                           (float4*)x_new, n4);
}